// Round 8
// baseline (1737.259 us; speedup 1.0000x reference)
//
#include <hip/hip_runtime.h>
#include <stdint.h>
#include <stddef.h>

// ---------------------------------------------------------------------------
// Sparse top-2 MoE, bf16 MFMA, fp32 accumulate.
//   convert: w1/w3/w2 fp32 -> bf16, tile-panel layout [e][p][q][128x64],
//            XOR-swizzled (chunk cs holds logical col cs^(r&7))  [proven r2-r6]
//   router:  logits -> softmax -> top2 -> per-expert compact lists (+x->bf16)
//   GU:      h = silu(x@w1^T) * (x@w3^T)   m201-style 4-phase/K-tile pipeline
//   Y:       out += coef * (h@w2^T)        literal m201 256x256 4-phase
// nt-major dispatch (proven): co-resident blocks share the weight panel (L2).
// m201 discipline per phase: {ds_reads + 1 half-tile stage (2 gload16/wave)}
//   -> sched_barrier -> s_barrier -> lgkmcnt(0) -> setprio(1) -> 16 MFMA ->
//   setprio(0) -> [counted vmcnt] -> s_barrier.   vmcnt never drains to 0.
// ws layout (MiB): [0,1) lists | [1,33) xb | [33,161) w1b (later w2b)
//                  [161,289) w3b | [289,418) hbuf
// ---------------------------------------------------------------------------

constexpr int kTokens  = 8192;
constexpr int kHidden  = 2048;
constexpr int kInter   = 4096;
constexpr int kExperts = 8;

constexpr int BM = 128, BN = 128, BK = 64;              // fallback tile
constexpr int MAX_MT = (2 * kTokens) / BM + kExperts;   // 136

constexpr int BM2 = 256;                                // main tile rows
constexpr int MAX_MT2 = (2 * kTokens) / BM2 + kExperts; // 72
constexpr int NT2 = kHidden / BK;                       // 32 K-tiles (GU)
constexpr int NTY = kInter / BK;                        // 64 K-tiles (Y)
constexpr int NPAN_GU = kInter / 128;                   // 32 B panels (GU pairs)
constexpr int NPAN_Y  = kHidden / 256;                  // 8 B panels (Y 256 cols)
constexpr int kSlotCap = 16512;                         // hbuf rows incl. slack

typedef short bf16x8 __attribute__((ext_vector_type(8)));
typedef float f32x4  __attribute__((ext_vector_type(4)));
typedef unsigned int u32;

__device__ __forceinline__ unsigned short f2bf(float f) {
  union { float f; unsigned u; } v; v.f = f;
  unsigned r = v.u + 0x7FFFu + ((v.u >> 16) & 1u);  // RTNE
  return (unsigned short)(r >> 16);
}

__device__ __forceinline__ void gload16(const void* g, void* l) {
  __builtin_amdgcn_global_load_lds(
      (const __attribute__((address_space(1))) u32*)g,
      (__attribute__((address_space(3))) u32*)l, 16, 0, 0);
}

#define SB0()    __builtin_amdgcn_sched_barrier(0)
#define BAR()    __builtin_amdgcn_s_barrier()
#define LGKM0()  asm volatile("s_waitcnt lgkmcnt(0)" ::: "memory")
#define VM(N)    asm volatile("s_waitcnt vmcnt(" #N ")" ::: "memory")

// ---------------------------- weight convert (round-2 proven) ---------------
__global__ __launch_bounds__(256) void convert_w(
    const float* __restrict__ src, unsigned short* __restrict__ dst,
    int lp, int lq, int K, long nchunks)
{
  long stride = (long)gridDim.x * blockDim.x;
  for (long g = blockIdx.x * (long)blockDim.x + threadIdx.x; g < nchunks; g += stride) {
    int  l   = (int)(g & 1023);
    long blk = g >> 10;
    int  q   = (int)(blk & ((1 << lq) - 1));
    long ep  = blk >> lq;
    int  p   = (int)(ep & ((1 << lp) - 1));
    int  e   = (int)(ep >> lp);
    int r = l >> 3, cs = l & 7, c = cs ^ (r & 7);
    size_t soff = (((size_t)(e << lp) + p) * 128 + r) * (size_t)K + (size_t)q * 64 + c * 8;
    float4 v0 = *reinterpret_cast<const float4*>(src + soff);
    float4 v1 = *reinterpret_cast<const float4*>(src + soff + 4);
    uint4 o;
    o.x = (u32)f2bf(v0.x) | ((u32)f2bf(v0.y) << 16);
    o.y = (u32)f2bf(v0.z) | ((u32)f2bf(v0.w) << 16);
    o.z = (u32)f2bf(v1.x) | ((u32)f2bf(v1.y) << 16);
    o.w = (u32)f2bf(v1.z) | ((u32)f2bf(v1.w) << 16);
    *reinterpret_cast<uint4*>(dst + g * 8) = o;
  }
}

// ---------------------------- router ----------------------------
__global__ __launch_bounds__(256) void moe_router(
    const float* __restrict__ x, const float* __restrict__ gate_w,
    unsigned short* __restrict__ xb, int* __restrict__ counts,
    int* __restrict__ list_idx, float* __restrict__ list_w)
{
  const int lane = threadIdx.x & 63;
  const int wave = threadIdx.x >> 6;
  const int t = blockIdx.x * 4 + wave;

  float acc[kExperts];
#pragma unroll
  for (int e = 0; e < kExperts; ++e) acc[e] = 0.f;

  const float4* xrow = reinterpret_cast<const float4*>(x + (size_t)t * kHidden);
#pragma unroll
  for (int j = 0; j < 8; ++j) {
    float4 xv = xrow[j * 64 + lane];
    uint2 pk;
    pk.x = (u32)f2bf(xv.x) | ((u32)f2bf(xv.y) << 16);
    pk.y = (u32)f2bf(xv.z) | ((u32)f2bf(xv.w) << 16);
    *reinterpret_cast<uint2*>(xb + (size_t)t * kHidden + j * 256 + lane * 4) = pk;
#pragma unroll
    for (int e = 0; e < kExperts; ++e) {
      float4 gv = reinterpret_cast<const float4*>(gate_w + (size_t)e * kHidden)[j * 64 + lane];
      acc[e] += xv.x * gv.x + xv.y * gv.y + xv.z * gv.z + xv.w * gv.w;
    }
  }
#pragma unroll
  for (int e = 0; e < kExperts; ++e) {
#pragma unroll
    for (int m = 32; m >= 1; m >>= 1) acc[e] += __shfl_xor(acc[e], m);
  }
  if (lane == 0) {
    float mx = acc[0];
#pragma unroll
    for (int e = 1; e < kExperts; ++e) mx = fmaxf(mx, acc[e]);
    float p[kExperts]; float s = 0.f;
#pragma unroll
    for (int e = 0; e < kExperts; ++e) { p[e] = __expf(acc[e] - mx); s += p[e]; }
    float inv = 1.f / s;
    int i1 = 0; float v1 = p[0];
#pragma unroll
    for (int e = 1; e < kExperts; ++e) if (p[e] > v1) { v1 = p[e]; i1 = e; }
    int i2 = (i1 == 0) ? 1 : 0; float v2 = p[i2];
#pragma unroll
    for (int e = 0; e < kExperts; ++e) {
      if (e == i1 || e == i2) continue;
      if (p[e] > v2) { v2 = p[e]; i2 = e; }
    }
    int s1 = atomicAdd(&counts[i1], 1);
    list_idx[i1 * kTokens + s1] = t;
    list_w [i1 * kTokens + s1] = v1 * inv;
    int s2 = atomicAdd(&counts[i2], 1);
    list_idx[i2 * kTokens + s2] = t;
    list_w [i2 * kTokens + s2] = v2 * inv;
  }
}

// ------------------- tile mapping helpers -------------------
__device__ __forceinline__ bool map_tile(const int* __restrict__ counts, int mt,
                                         int& e, int& lm, int& sb, int& ne)
{
  int tb = 0; sb = 0;
  for (e = 0; e < kExperts; ++e) {
    ne = counts[e];
    int tiles = (ne + BM - 1) / BM;
    if (mt < tb + tiles) { lm = mt - tb; return true; }
    tb += tiles; sb += ne;
  }
  return false;
}

__device__ __forceinline__ bool map_tile2(const int* __restrict__ counts, int mt,
                                          int& e, int& lm, int& sb, int& ne)
{
  int tb = 0; sb = 0;
  for (e = 0; e < kExperts; ++e) {
    ne = counts[e];
    int tiles = (ne + BM2 - 1) / BM2;
    if (mt < tb + tiles) { lm = mt - tb; return true; }
    tb += tiles; sb += ne;
  }
  return false;
}

// ------------- GU GEMM: m201-style 4-phase/K-tile -------------
// Tile 256 rows x (128 G-cols + 128 U-cols). 8 waves: wr=w>>2 row-half,
// wc=w&3 col-quarter (32 cols). LDS buf b: A-h0 @ b*16384, A-h1 @ +8192,
// B1 @ 32768+b*8192, B3 @ 49152+b*8192 (shorts). 128 KB total.
// Stage ring (per phase, 1 unit = 2 gload16/thread):
//   s.P1 -> B1(s+1) | s.P2 -> B3(s+1) | s.P3 -> A0(s+2) | s.P4 -> A1(s+2)
// Waits (derived from per-thread queue): vmcnt(8) @ end-P2, vmcnt(6) @ end-P4.
__global__ __launch_bounds__(512, 2) void moe_gu4(
    const unsigned short* __restrict__ xb,
    const unsigned short* __restrict__ w1b, const unsigned short* __restrict__ w3b,
    const int* __restrict__ counts, const int* __restrict__ list_idx,
    unsigned short* __restrict__ hbuf)
{
  __shared__ unsigned short lds[65536];
  __shared__ int toks[BM2];

  const int tid = threadIdx.x;
  const int nt  = blockIdx.x / MAX_MT2;   // nt-major
  const int mt  = blockIdx.x % MAX_MT2;

  int e, lm, sb, ne;
  if (!map_tile2(counts, mt, e, lm, sb, ne)) return;
  const int row0 = lm * BM2;

  if (tid < BM2) {
    int lr = row0 + tid;
    toks[tid] = list_idx[e * kTokens + ((lr < ne) ? lr : 0)];
  }
  __syncthreads();

  const int lane = tid & 63;
  const int w    = tid >> 6;
  const int wr   = w >> 2;   // 0..1
  const int wc   = w & 3;    // 0..3

  // staging sources
  const unsigned short* srcA[2][2];   // [h][j]
  int cOff[2];
#pragma unroll
  for (int j = 0; j < 2; ++j) {
    int l = (w * 2 + j) * 64 + lane;
    int r = l >> 3, c = (l & 7) ^ (r & 7);
#pragma unroll
    for (int h = 0; h < 2; ++h)
      srcA[h][j] = xb + (size_t)toks[h * 128 + r] * kHidden + c * 8;
    cOff[j] = l * 8;
  }
  const unsigned short* pB1 = w1b + (size_t)(e * NPAN_GU + nt) * NT2 * 8192;
  const unsigned short* pB3 = w3b + (size_t)(e * NPAN_GU + nt) * NT2 * 8192;

  f32x4 accG[8][2], accU[8][2];
  const f32x4 zero = {0.f, 0.f, 0.f, 0.f};
#pragma unroll
  for (int m = 0; m < 8; ++m)
#pragma unroll
    for (int n = 0; n < 2; ++n) { accG[m][n] = zero; accU[m][n] = zero; }

  const int dA = (w * 2) * 512;   // LDS dest base offset within a unit (shorts)

  // ---- prologue: B1(0),B3(0),A0(0),A1(0) -> buf0; A0(1),A1(1) -> buf1 ----
#pragma unroll
  for (int j = 0; j < 2; ++j) gload16(pB1 + cOff[j], &lds[32768 + dA + j * 512]);
#pragma unroll
  for (int j = 0; j < 2; ++j) gload16(pB3 + cOff[j], &lds[49152 + dA + j * 512]);
#pragma unroll
  for (int j = 0; j < 2; ++j) gload16(srcA[0][j], &lds[0 + dA + j * 512]);
#pragma unroll
  for (int j = 0; j < 2; ++j) gload16(srcA[1][j], &lds[8192 + dA + j * 512]);
#pragma unroll
  for (int j = 0; j < 2; ++j) gload16(srcA[0][j] + BK, &lds[16384 + dA + j * 512]);
#pragma unroll
  for (int j = 0; j < 2; ++j) gload16(srcA[1][j] + BK, &lds[24576 + dA + j * 512]);
  SB0(); VM(4); SB0(); BAR();

  for (int s2 = 0; s2 < NT2; s2 += 2) {
#pragma unroll
    for (int u = 0; u < 2; ++u) {
      const int s  = s2 + u;
      const int b  = u, nb = u ^ 1;
      const int sp1 = (s + 1 < NT2) ? (s + 1) : (NT2 - 1);
      const int sp2 = (s + 2 < NT2) ? (s + 2) : (NT2 - 1);
      const int aub = b * 16384 + wr * 8192;   // this wave's A unit
      const int b1b = 32768 + b * 8192;
      const int b3b = 49152 + b * 8192;

      bf16x8 a0[4][2], a1[4][2], b1f[2][2], b3f[2][2];

      // ================= P1: reads a0+b1 | stage B1(s+1) | G mh0 ===========
#pragma unroll
      for (int m = 0; m < 4; ++m) {
        const int rr = m * 16 + (lane & 15);
#pragma unroll
        for (int kk = 0; kk < 2; ++kk) {
          const int cq = kk * 4 + (lane >> 4);
          a0[m][kk] = *reinterpret_cast<const bf16x8*>(&lds[aub + rr * 64 + ((cq ^ (rr & 7)) << 3)]);
        }
      }
#pragma unroll
      for (int n = 0; n < 2; ++n) {
        const int rr = wc * 32 + n * 16 + (lane & 15);
#pragma unroll
        for (int kk = 0; kk < 2; ++kk) {
          const int cq = kk * 4 + (lane >> 4);
          b1f[n][kk] = *reinterpret_cast<const bf16x8*>(&lds[b1b + rr * 64 + ((cq ^ (rr & 7)) << 3)]);
        }
      }
#pragma unroll
      for (int j = 0; j < 2; ++j)
        gload16(pB1 + (size_t)sp1 * 8192 + cOff[j], &lds[32768 + nb * 8192 + dA + j * 512]);
      SB0(); BAR(); LGKM0(); SB0();
      __builtin_amdgcn_s_setprio(1);
#pragma unroll
      for (int m = 0; m < 4; ++m)
#pragma unroll
        for (int n = 0; n < 2; ++n)
#pragma unroll
          for (int kk = 0; kk < 2; ++kk)
            accG[m][n] = __builtin_amdgcn_mfma_f32_16x16x32_bf16(a0[m][kk], b1f[n][kk], accG[m][n], 0, 0, 0);
      __builtin_amdgcn_s_setprio(0);
      SB0(); BAR();

      // ================= P2: reads a1 | stage B3(s+1) | G mh1 | vmcnt(8) ====
#pragma unroll
      for (int m = 0; m < 4; ++m) {
        const int rr = 64 + m * 16 + (lane & 15);
#pragma unroll
        for (int kk = 0; kk < 2; ++kk) {
          const int cq = kk * 4 + (lane >> 4);
          a1[m][kk] = *reinterpret_cast<const bf16x8*>(&lds[aub + rr * 64 + ((cq ^ (rr & 7)) << 3)]);
        }
      }
#pragma unroll
      for (int j = 0; j < 2; ++j)
        gload16(pB3 + (size_t)sp1 * 8192 + cOff[j], &lds[49152 + nb * 8192 + dA + j * 512]);
      SB0(); BAR(); LGKM0(); SB0();
      __builtin_amdgcn_s_setprio(1);
#pragma unroll
      for (int m = 0; m < 4; ++m)
#pragma unroll
        for (int n = 0; n < 2; ++n)
#pragma unroll
          for (int kk = 0; kk < 2; ++kk)
            accG[4 + m][n] = __builtin_amdgcn_mfma_f32_16x16x32_bf16(a1[m][kk], b1f[n][kk], accG[4 + m][n], 0, 0, 0);
      __builtin_amdgcn_s_setprio(0);
      SB0(); VM(8); BAR();

      // ================= P3: reads b3 | stage A0(s+2) | U mh0 ==============
#pragma unroll
      for (int n = 0; n < 2; ++n) {
        const int rr = wc * 32 + n * 16 + (lane & 15);
#pragma unroll
        for (int kk = 0; kk < 2; ++kk) {
          const int cq = kk * 4 + (lane >> 4);
          b3f[n][kk] = *reinterpret_cast<const bf16x8*>(&lds[b3b + rr * 64 + ((cq ^ (rr & 7)) << 3)]);
        }
      }
#pragma unroll
      for (int j = 0; j < 2; ++j)
        gload16(srcA[0][j] + sp2 * BK, &lds[b * 16384 + dA + j * 512]);
      SB0(); BAR(); LGKM0(); SB0();
      __builtin_amdgcn_s_setprio(1);
#pragma unroll
      for (int m = 0; m < 4; ++m)
#pragma unroll
        for (int n = 0; n < 2; ++n)
#pragma unroll
          for (int kk = 0; kk < 2; ++kk)
            accU[m][n] = __builtin_amdgcn_mfma_f32_16x16x32_bf16(a0[m][kk], b3f[n][kk], accU[m][n], 0, 0, 0);
      __builtin_amdgcn_s_setprio(0);
      SB0(); BAR();

      // ================= P4: stage A1(s+2) | U mh1 | vmcnt(6) ==============
#pragma unroll
      for (int j = 0; j < 2; ++j)
        gload16(srcA[1][j] + sp2 * BK, &lds[b * 16384 + 8192 + dA + j * 512]);
      SB0(); BAR(); LGKM0(); SB0();
      __builtin_amdgcn_s_setprio(1);
#pragma unroll
      for (int m = 0; m < 4; ++m)
#pragma unroll
        for (int n = 0; n < 2; ++n)
#pragma unroll
          for (int kk = 0; kk < 2; ++kk)
            accU[4 + m][n] = __builtin_amdgcn_mfma_f32_16x16x32_bf16(a1[m][kk], b3f[n][kk], accU[4 + m][n], 0, 0, 0);
      __builtin_amdgcn_s_setprio(0);
      SB0(); VM(6); BAR();
    }
  }

  // epilogue: h = silu(g)*u
#pragma unroll
  for (int am = 0; am < 8; ++am) {
#pragma unroll
    for (int r = 0; r < 4; ++r) {
      int rloc = wr * 128 + am * 16 + ((lane >> 4) * 4) + r;
      int lrow = row0 + rloc;
      if (lrow < ne) {
        size_t base = (size_t)(sb + lrow) * kInter + (size_t)nt * 128 + wc * 32 + (lane & 15);
#pragma unroll
        for (int n = 0; n < 2; ++n) {
          float g = accG[am][n][r];
          float u = accU[am][n][r];
          float hv = (g / (1.f + __expf(-g))) * u;
          hbuf[base + n * 16] = f2bf(hv);
        }
      }
    }
  }
}

// ------------- Y GEMM: literal m201 256x256, 4-phase/K-tile -------------
// 8 waves: wr row-half (128), wc col-quarter (64 of 256). LDS buf b:
// A-h0 @ b*16384, A-h1 @ +8192, B-h0 @ 32768+b*16384, B-h1 @ +8192.
// Stage ring: s.P1->B0(s+1) | s.P2->B1(s+1) | s.P3->A0(s+2) | s.P4->A1(s+2).
// Wait: vmcnt(4) @ end-P4 (forces all of tile s+1).
__global__ __launch_bounds__(512, 2) void moe_y4(
    const unsigned short* __restrict__ hbuf,
    const unsigned short* __restrict__ w2b,
    const int* __restrict__ counts, const int* __restrict__ list_idx,
    const float* __restrict__ list_w,
    float* __restrict__ out)
{
  __shared__ unsigned short lds[65536];
  __shared__ int   toks[BM2];
  __shared__ float cofs[BM2];

  const int tid = threadIdx.x;
  const int nt  = blockIdx.x / MAX_MT2;   // nt-major, 8 panels of 256 cols
  const int mt  = blockIdx.x % MAX_MT2;

  int e, lm, sb, ne;
  if (!map_tile2(counts, mt, e, lm, sb, ne)) return;
  const int row0 = lm * BM2;

  if (tid < BM2) {
    int lr = row0 + tid;
    bool v = lr < ne;
    toks[tid] = v ? list_idx[e * kTokens + lr] : 0;
    cofs[tid] = v ? list_w [e * kTokens + lr] : 0.f;
  }
  __syncthreads();

  const int lane = tid & 63;
  const int w    = tid >> 6;
  const int wr   = w >> 2;   // 0..1 row-half
  const int wc   = w & 3;    // 0..3 col-quarter (64 cols)

  const unsigned short* srcA[2][2];
  int cOff[2];
#pragma unroll
  for (int j = 0; j < 2; ++j) {
    int l = (w * 2 + j) * 64 + lane;
    int r = l >> 3, c = (l & 7) ^ (r & 7);
#pragma unroll
    for (int h = 0; h < 2; ++h) {
      int rg = sb + row0 + h * 128 + r;
      if (rg > kSlotCap - 1) rg = kSlotCap - 1;
      srcA[h][j] = hbuf + (size_t)rg * kInter + c * 8;
    }
    cOff[j] = l * 8;
  }
  // B halves = 128-row convert panels 2*nt and 2*nt+1 (lp=4 layout)
  const unsigned short* pB[2];
#pragma unroll
  for (int h = 0; h < 2; ++h)
    pB[h] = w2b + (size_t)(e * 16 + nt * 2 + h) * NTY * 8192;

  f32x4 acc[8][4];
  const f32x4 zero = {0.f, 0.f, 0.f, 0.f};
#pragma unroll
  for (int m = 0; m < 8; ++m)
#pragma unroll
    for (int n = 0; n < 4; ++n) acc[m][n] = zero;

  const int dA = (w * 2) * 512;
  const int bwh = wc >> 1;            // this wave's B half
  const int brr0 = (wc & 1) * 64;     // row base within the half

  // ---- prologue: B0(0),B1(0),A0(0),A1(0) -> buf0; A0(1),A1(1) -> buf1 ----
#pragma unroll
  for (int j = 0; j < 2; ++j) gload16(pB[0] + cOff[j], &lds[32768 + dA + j * 512]);
#pragma unroll
  for (int j = 0; j < 2; ++j) gload16(pB[1] + cOff[j], &lds[40960 + dA + j * 512]);
#pragma unroll
  for (int j = 0; j < 2; ++j) gload16(srcA[0][j], &lds[0 + dA + j * 512]);
#pragma unroll
  for (int j = 0; j < 2; ++j) gload16(srcA[1][j], &lds[8192 + dA + j * 512]);
#pragma unroll
  for (int j = 0; j < 2; ++j) gload16(srcA[0][j] + BK, &lds[16384 + dA + j * 512]);
#pragma unroll
  for (int j = 0; j < 2; ++j) gload16(srcA[1][j] + BK, &lds[24576 + dA + j * 512]);
  SB0(); VM(4); SB0(); BAR();

  for (int s2 = 0; s2 < NTY; s2 += 2) {
#pragma unroll
    for (int u = 0; u < 2; ++u) {
      const int s  = s2 + u;
      const int b  = u, nb = u ^ 1;
      const int sp1 = (s + 1 < NTY) ? (s + 1) : (NTY - 1);
      const int sp2 = (s + 2 < NTY) ? (s + 2) : (NTY - 1);
      const int aub = b * 16384 + wr * 8192;
      const int bub = 32768 + b * 16384 + bwh * 8192;

      bf16x8 a0[4][2], a1[4][2], b01[2][2], b23[2][2];

      // ===== P1: reads a0 + b(n=0,1) | stage B0(s+1) | Q(mh0,n01) ==========
#pragma unroll
      for (int m = 0; m < 4; ++m) {
        const int rr = m * 16 + (lane & 15);
#pragma unroll
        for (int kk = 0; kk < 2; ++kk) {
          const int cq = kk * 4 + (lane >> 4);
          a0[m][kk] = *reinterpret_cast<const bf16x8*>(&lds[aub + rr * 64 + ((cq ^ (rr & 7)) << 3)]);
        }
      }
#pragma unroll
      for (int n = 0; n < 2; ++n) {
        const int rr = brr0 + n * 16 + (lane & 15);
#pragma unroll
        for (int kk = 0; kk < 2; ++kk) {
          const int cq = kk * 4 + (lane >> 4);
          b01[n][kk] = *reinterpret_cast<const bf16x8*>(&lds[bub + rr * 64 + ((cq ^ (rr & 7)) << 3)]);
        }
      }
#pragma unroll
      for (int j = 0; j < 2; ++j)
        gload16(pB[0] + (size_t)sp1 * 8192 + cOff[j], &lds[32768 + nb * 16384 + dA + j * 512]);
      SB0(); BAR(); LGKM0(); SB0();
      __builtin_amdgcn_s_setprio(1);
#pragma unroll
      for (int m = 0; m < 4; ++m)
#pragma unroll
        for (int n = 0; n < 2; ++n)
#pragma unroll
          for (int kk = 0; kk < 2; ++kk)
            acc[m][n] = __builtin_amdgcn_mfma_f32_16x16x32_bf16(a0[m][kk], b01[n][kk], acc[m][n], 0, 0, 0);
      __builtin_amdgcn_s_setprio(0);
      SB0(); BAR();

      // ===== P2: reads a1 | stage B1(s+1) | Q(mh1,n01) =====================
#pragma unroll
      for (int m = 0; m < 4; ++m) {
        const int rr = 64 + m * 16 + (lane & 15);
#pragma unroll
        for (int kk = 0; kk < 2; ++kk) {
          const int cq = kk * 4 + (lane >> 4);
          a1[m][kk] = *reinterpret_cast<const bf16x8*>(&lds[aub + rr * 64 + ((cq ^ (rr & 7)) << 3)]);
        }
      }
#pragma unroll
      for (int j = 0; j < 2; ++j)
        gload16(pB[1] + (size_t)sp1 * 8192 + cOff[j], &lds[40960 + nb * 16384 + dA + j * 512]);
      SB0(); BAR(); LGKM0(); SB0();
      __builtin_amdgcn_s_setprio(1);
#pragma unroll
      for (int m = 0; m < 4; ++m)
#pragma unroll
        for (int n = 0; n < 2; ++n)
#pragma unroll
          for (int kk = 0; kk < 2; ++kk)
            acc[4 + m][n] = __builtin_amdgcn_mfma_f32_16x16x32_bf16(a1[m][kk], b01[n][kk], acc[4 + m][n], 0, 0, 0);
      __builtin_amdgcn_s_setprio(0);
      SB0(); BAR();

      // ===== P3: reads b(n=2,3) | stage A0(s+2) | Q(mh0,n23) ===============
#pragma unroll
      for (int n = 0; n < 2; ++n) {
        const int rr = brr0 + 32 + n * 16 + (lane & 15);
#pragma unroll
        for (int kk = 0; kk < 2; ++kk) {
          const int cq = kk * 4 + (lane >> 4);
          b23[n][kk] = *reinterpret_cast<const bf16x8*>(&lds[bub + rr * 64 + ((cq ^ (rr & 7)) << 3)]);
        }
      }
#pragma unroll
      for (int j = 0; j < 2; ++j)
        gload16(srcA[0][j] + sp2 * BK, &lds[b * 16384 + dA + j * 512]);
      SB0(); BAR(); LGKM0(); SB0();
      __builtin_amdgcn_s_setprio(1);
#pragma unroll
      for (int m = 0; m < 4; ++m)
#pragma unroll
        for (int n = 0; n < 2; ++n)
#pragma unroll
          for (int kk = 0; kk < 2; ++kk)
            acc[m][2 + n] = __builtin_amdgcn_mfma_f32_16x16x32_bf16(a0[m][kk], b23[n][kk], acc[m][2 + n], 0, 0, 0);
      __builtin_amdgcn_s_setprio(0);
      SB0(); BAR();

      // ===== P4: stage A1(s+2) | Q(mh1,n23) | vmcnt(4) =====================
#pragma unroll
      for (int j = 0; j < 2; ++j)
        gload16(srcA[1][j] + sp2 * BK, &lds[b * 16384 + 8192 + dA + j * 512]);
      SB0(); BAR(); LGKM0(); SB0();
      __builtin_amdgcn_s_setprio(1);
#pragma unroll
      for (int m = 0; m < 4; ++m)
#pragma unroll
        for (int n = 0; n < 2; ++n)
#pragma unroll
          for (int kk = 0; kk < 2; ++kk)
            acc[4 + m][2 + n] = __builtin_amdgcn_mfma_f32_16x16x32_bf16(a1[m][kk], b23[n][kk], acc[4 + m][2 + n], 0, 0, 0);
      __builtin_amdgcn_s_setprio(0);
      SB0(); VM(4); BAR();
    }
  }

  // epilogue: out[token] += coef * y
#pragma unroll
  for (int am = 0; am < 8; ++am) {
#pragma unroll
    for (int r = 0; r < 4; ++r) {
      int rloc = wr * 128 + am * 16 + ((lane >> 4) * 4) + r;
      if (row0 + rloc < ne) {
        float cf = cofs[rloc];
        size_t obase = (size_t)toks[rloc] * kHidden + (size_t)nt * 256 + wc * 64 + (lane & 15);
#pragma unroll
        for (int n = 0; n < 4; ++n)
          atomicAdd(&out[obase + n * 16], cf * acc[am][n][r]);
      }
    }
  }
}

// ===================== fallback (fp32 on-the-fly) ============
__global__ __launch_bounds__(256, 2) void moe_gu_f32(
    const unsigned short* __restrict__ xb,
    const float* __restrict__ w1, const float* __restrict__ w3,
    const int* __restrict__ counts, const int* __restrict__ list_idx,
    unsigned short* __restrict__ hbuf)
{
  __shared__ unsigned short As [BM * BK];
  __shared__ unsigned short B1s[BN * BK];
  __shared__ unsigned short B3s[BN * BK];
  __shared__ int toks[BM];

  const int tid = threadIdx.x;
  const int nt  = blockIdx.x / MAX_MT;
  const int mt  = blockIdx.x % MAX_MT;

  int e, lm, sb, ne;
  if (!map_tile(counts, mt, e, lm, sb, ne)) return;
  const int row0 = lm * BM;

  if (tid < BM) {
    int lr = row0 + tid;
    toks[tid] = list_idx[e * kTokens + ((lr < ne) ? lr : 0)];
  }
  __syncthreads();

  const unsigned short* aptr[4];
#pragma unroll
  for (int i = 0; i < 4; ++i) {
    int chunk = i * 256 + tid;
    int r = chunk >> 3, c8 = chunk & 7;
    aptr[i] = xb + (size_t)toks[r] * kHidden + c8 * 8;
  }
  const float* w1e = w1 + (size_t)e * kInter * kHidden;
  const float* w3e = w3 + (size_t)e * kInter * kHidden;

  f32x4 accG[4][4], accU[4][4];
  const f32x4 zero = {0.f, 0.f, 0.f, 0.f};
#pragma unroll
  for (int m = 0; m < 4; ++m)
#pragma unroll
    for (int n = 0; n < 4; ++n) { accG[m][n] = zero; accU[m][n] = zero; }

  const int lane = tid & 63;
  const int wr = (tid >> 6) >> 1;
  const int wc = (tid >> 6) & 1;

  for (int k0 = 0; k0 < kHidden; k0 += BK) {
#pragma unroll
    for (int i = 0; i < 4; ++i) {
      int chunk = i * 256 + tid;
      uint4 v = *reinterpret_cast<const uint4*>(aptr[i] + k0);
      *reinterpret_cast<uint4*>(&As[chunk * 8]) = v;
    }
#pragma unroll
    for (int i = 0; i < 8; ++i) {
      int c = i * 256 + tid;
      int rowB = c >> 4, c16 = c & 15;
      size_t off = ((size_t)(nt * BN + rowB)) * kHidden + k0 + c16 * 4;
      float4 v1 = *reinterpret_cast<const float4*>(w1e + off);
      float4 v3 = *reinterpret_cast<const float4*>(w3e + off);
      uint2 p1, p3;
      p1.x = (u32)f2bf(v1.x) | ((u32)f2bf(v1.y) << 16);
      p1.y = (u32)f2bf(v1.z) | ((u32)f2bf(v1.w) << 16);
      p3.x = (u32)f2bf(v3.x) | ((u32)f2bf(v3.y) << 16);
      p3.y = (u32)f2bf(v3.z) | ((u32)f2bf(v3.w) << 16);
      *reinterpret_cast<uint2*>(&B1s[rowB * BK + c16 * 4]) = p1;
      *reinterpret_cast<uint2*>(&B3s[rowB * BK + c16 * 4]) = p3;
    }
    __syncthreads();
#pragma unroll
    for (int kk = 0; kk < 2; ++kk) {
      const int klo = kk * 32 + (lane >> 4) * 8;
      bf16x8 a[4], b1v[4], b3v[4];
#pragma unroll
      for (int m = 0; m < 4; ++m)
        a[m] = *reinterpret_cast<const bf16x8*>(&As[(wr * 64 + m * 16 + (lane & 15)) * BK + klo]);
#pragma unroll
      for (int n = 0; n < 4; ++n) {
        b1v[n] = *reinterpret_cast<const bf16x8*>(&B1s[(wc * 64 + n * 16 + (lane & 15)) * BK + klo]);
        b3v[n] = *reinterpret_cast<const bf16x8*>(&B3s[(wc * 64 + n * 16 + (lane & 15)) * BK + klo]);
      }
#pragma unroll
      for (int m = 0; m < 4; ++m)
#pragma unroll
        for (int n = 0; n < 4; ++n) {
          accG[m][n] = __builtin_amdgcn_mfma_f32_16x16x32_bf16(a[m], b1v[n], accG[m][n], 0, 0, 0);
          accU[m][n] = __builtin_amdgcn_mfma_f32_16x16x32_bf16(a[m], b3v[n], accU[m][n], 0, 0, 0);
        }
    }
    __syncthreads();
  }
#pragma unroll
  for (int m = 0; m < 4; ++m) {
#pragma unroll
    for (int r = 0; r < 4; ++r) {
      int rloc = wr * 64 + m * 16 + ((lane >> 4) * 4) + r;
      int lrow = row0 + rloc;
      if (lrow < ne) {
        size_t base = (size_t)(sb + lrow) * kInter + (size_t)nt * BN + wc * 64 + (lane & 15);
#pragma unroll
        for (int n = 0; n < 4; ++n) {
          float g = accG[m][n][r];
          float u = accU[m][n][r];
          hbuf[base + n * 16] = f2bf((g / (1.f + __expf(-g))) * u);
        }
      }
    }
  }
}

__global__ __launch_bounds__(256, 2) void moe_y_f32(
    const unsigned short* __restrict__ hbuf,
    const float* __restrict__ w2,
    const int* __restrict__ counts, const int* __restrict__ list_idx,
    const float* __restrict__ list_w,
    float* __restrict__ out)
{
  __shared__ unsigned short As[BM * BK];
  __shared__ unsigned short Bs[BN * BK];
  __shared__ int   toks[BM];
  __shared__ float cofs[BM];

  const int tid = threadIdx.x;
  const int nt  = blockIdx.x / MAX_MT;
  const int mt  = blockIdx.x % MAX_MT;

  int e, lm, sb, ne;
  if (!map_tile(counts, mt, e, lm, sb, ne)) return;
  const int row0 = lm * BM;

  if (tid < BM) {
    int lr = row0 + tid;
    bool v = lr < ne;
    toks[tid] = v ? list_idx[e * kTokens + lr] : 0;
    cofs[tid] = v ? list_w [e * kTokens + lr] : 0.f;
  }
  __syncthreads();

  const float* w2e = w2 + (size_t)e * kHidden * kInter;
  const unsigned short* arow = hbuf + (size_t)(sb + row0) * kInter;

  f32x4 acc[4][4];
  const f32x4 zero = {0.f, 0.f, 0.f, 0.f};
#pragma unroll
  for (int m = 0; m < 4; ++m)
#pragma unroll
    for (int n = 0; n < 4; ++n) acc[m][n] = zero;

  const int lane = tid & 63;
  const int wr = (tid >> 6) >> 1;
  const int wc = (tid >> 6) & 1;

  for (int k0 = 0; k0 < kInter; k0 += BK) {
#pragma unroll
    for (int i = 0; i < 4; ++i) {
      int chunk = i * 256 + tid;
      int r = chunk >> 3, c8 = chunk & 7;
      uint4 v = *reinterpret_cast<const uint4*>(arow + (size_t)r * kInter + k0 + c8 * 8);
      *reinterpret_cast<uint4*>(&As[chunk * 8]) = v;
    }
#pragma unroll
    for (int i = 0; i < 8; ++i) {
      int c = i * 256 + tid;
      int rowB = c >> 4, c16 = c & 15;
      size_t off = ((size_t)(nt * BN + rowB)) * kInter + k0 + c16 * 4;
      float4 v2 = *reinterpret_cast<const float4*>(w2e + off);
      uint2 p2;
      p2.x = (u32)f2bf(v2.x) | ((u32)f2bf(v2.y) << 16);
      p2.y = (u32)f2bf(v2.z) | ((u32)f2bf(v2.w) << 16);
      *reinterpret_cast<uint2*>(&Bs[rowB * BK + c16 * 4]) = p2;
    }
    __syncthreads();
#pragma unroll
    for (int kk = 0; kk < 2; ++kk) {
      const int klo = kk * 32 + (lane >> 4) * 8;
      bf16x8 a[4], b[4];
#pragma unroll
      for (int m = 0; m < 4; ++m)
        a[m] = *reinterpret_cast<const bf16x8*>(&As[(wr * 64 + m * 16 + (lane & 15)) * BK + klo]);
#pragma unroll
      for (int n = 0; n < 4; ++n)
        b[n] = *reinterpret_cast<const bf16x8*>(&Bs[(wc * 64 + n * 16 + (lane & 15)) * BK + klo]);
#pragma unroll
      for (int m = 0; m < 4; ++m)
#pragma unroll
        for (int n = 0; n < 4; ++n)
          acc[m][n] = __builtin_amdgcn_mfma_f32_16x16x32_bf16(a[m], b[n], acc[m][n], 0, 0, 0);
    }
    __syncthreads();
  }
#pragma unroll
  for (int m = 0; m < 4; ++m) {
#pragma unroll
    for (int r = 0; r < 4; ++r) {
      int rloc = wr * 64 + m * 16 + ((lane >> 4) * 4) + r;
      if (row0 + rloc < ne) {
        float cf = cofs[rloc];
        size_t obase = (size_t)toks[rloc] * kHidden + (size_t)nt * BN + wc * 64 + (lane & 15);
#pragma unroll
        for (int n = 0; n < 4; ++n)
          atomicAdd(&out[obase + n * 16], cf * acc[m][n][r]);
      }
    }
  }
}

// ---------------------------- host ----------------------------
extern "C" void kernel_launch(void* const* d_in, const int* in_sizes, int n_in,
                              void* d_out, int out_size, void* d_ws, size_t ws_size,
                              hipStream_t stream)
{
  const float* x      = (const float*)d_in[0];
  const float* gate_w = (const float*)d_in[1];
  const float* w1     = (const float*)d_in[2];
  const float* w2     = (const float*)d_in[3];
  const float* w3     = (const float*)d_in[4];
  float* out = (float*)d_out;

  char* ws = (char*)d_ws;
  const size_t MiB = 1ull << 20;
  int*   counts   = (int*)(ws);
  int*   list_idx = (int*)(ws + 1024);
  float* list_w   = (float*)(ws + 1024 + kExperts * kTokens * 4);

  hipMemsetAsync(counts, 0, 1024, stream);
  hipMemsetAsync(out, 0, (size_t)kTokens * kHidden * sizeof(float), stream);

  if (ws_size >= 418 * MiB) {
    unsigned short* xb   = (unsigned short*)(ws + 1 * MiB);
    unsigned short* w1b  = (unsigned short*)(ws + 33 * MiB);
    unsigned short* w3b  = (unsigned short*)(ws + 161 * MiB);
    unsigned short* hbuf = (unsigned short*)(ws + 289 * MiB);
    unsigned short* w2b  = w1b;  // reuse after GU

    const long nch = (long)kExperts * 32 * 32 * 1024;  // same count for w2 (16*64)
    convert_w<<<4096, 256, 0, stream>>>(w1, w1b, 5, 5, kHidden, nch);
    convert_w<<<4096, 256, 0, stream>>>(w3, w3b, 5, 5, kHidden, nch);
    moe_router<<<kTokens / 4, 256, 0, stream>>>(x, gate_w, xb, counts, list_idx, list_w);
    moe_gu4<<<NPAN_GU * MAX_MT2, 512, 0, stream>>>(xb, w1b, w3b, counts, list_idx, hbuf);
    convert_w<<<4096, 256, 0, stream>>>(w2, w2b, 4, 6, kInter, nch);
    moe_y4<<<NPAN_Y * MAX_MT2, 512, 0, stream>>>(hbuf, w2b, counts, list_idx, list_w, out);
  } else {
    unsigned short* xb   = (unsigned short*)(ws + 1 * MiB);
    unsigned short* hbuf = (unsigned short*)(ws + 36 * MiB);
    moe_router<<<kTokens / 4, 256, 0, stream>>>(x, gate_w, xb, counts, list_idx, list_w);
    moe_gu_f32<<<(kInter / BN) * MAX_MT, 256, 0, stream>>>(xb, w1, w3, counts, list_idx, hbuf);
    moe_y_f32 <<<(kHidden / BN) * MAX_MT, 256, 0, stream>>>(hbuf, w2, counts, list_idx, list_w, out);
  }
}

// Round 9
// 1444.249 us; speedup vs baseline: 1.2029x; 1.2029x over previous
//
#include <hip/hip_runtime.h>
#include <stdint.h>
#include <stddef.h>

// ---------------------------------------------------------------------------
// Sparse top-2 MoE, bf16 MFMA, fp32 accumulate.
//   convert: w1/w3/w2 fp32 -> bf16, tile-panel layout [e][p][q][128x64],
//            XOR-swizzled (chunk cs holds logical col cs^(r&7))  [proven r2]
//   router:  logits -> softmax -> top2 -> per-expert lists, idx packed t*2+rank
//   GU:      h = silu(x@w1^T) * (x@w3^T)   [byte-exact r2 structure, 625us]
//   Y:       ybuf[rank][tok] = coef*(h@w2^T)  plain stores (NO atomics),
//            256-col panels (halves hbuf re-reads), 512thr/16 waves/CU
//   merge:   out = ybuf0 + ybuf1           (replaces 33M atomicAdds + memset)
// nt-major dispatch: co-resident blocks share the weight panel (L2-hot).
// ws layout (MiB): [0,1) lists | [1,33) xb | [33,161) w1b (later w2b)
//                  [161,289) w3b (later ybuf[2]) | [289,418) hbuf
// ---------------------------------------------------------------------------

constexpr int kTokens  = 8192;
constexpr int kHidden  = 2048;
constexpr int kInter   = 4096;
constexpr int kExperts = 8;

constexpr int BM = 128, BN = 128, BK = 64;
constexpr int MAX_MT = (2 * kTokens) / BM + kExperts;   // 136
constexpr int NTY = kInter / BK;                        // 64 K-tiles (Y)
constexpr int NPAN_Y5 = kHidden / 256;                  // 8 Y panels
constexpr int kSlotCap = 16512;                         // hbuf rows incl. slack

typedef short bf16x8 __attribute__((ext_vector_type(8)));
typedef float f32x4  __attribute__((ext_vector_type(4)));
typedef unsigned int u32;

__device__ __forceinline__ unsigned short f2bf(float f) {
  union { float f; unsigned u; } v; v.f = f;
  unsigned r = v.u + 0x7FFFu + ((v.u >> 16) & 1u);  // RTNE
  return (unsigned short)(r >> 16);
}

__device__ __forceinline__ void gload16(const void* g, void* l) {
  __builtin_amdgcn_global_load_lds(
      (const __attribute__((address_space(1))) u32*)g,
      (__attribute__((address_space(3))) u32*)l, 16, 0, 0);
}

// ---------------------------- weight convert (proven r2) --------------------
__global__ __launch_bounds__(256) void convert_w(
    const float* __restrict__ src, unsigned short* __restrict__ dst,
    int lp, int lq, int K, long nchunks)
{
  long stride = (long)gridDim.x * blockDim.x;
  for (long g = blockIdx.x * (long)blockDim.x + threadIdx.x; g < nchunks; g += stride) {
    int  l   = (int)(g & 1023);
    long blk = g >> 10;
    int  q   = (int)(blk & ((1 << lq) - 1));
    long ep  = blk >> lq;
    int  p   = (int)(ep & ((1 << lp) - 1));
    int  e   = (int)(ep >> lp);
    int r = l >> 3, cs = l & 7, c = cs ^ (r & 7);
    size_t soff = (((size_t)(e << lp) + p) * 128 + r) * (size_t)K + (size_t)q * 64 + c * 8;
    float4 v0 = *reinterpret_cast<const float4*>(src + soff);
    float4 v1 = *reinterpret_cast<const float4*>(src + soff + 4);
    uint4 o;
    o.x = (u32)f2bf(v0.x) | ((u32)f2bf(v0.y) << 16);
    o.y = (u32)f2bf(v0.z) | ((u32)f2bf(v0.w) << 16);
    o.z = (u32)f2bf(v1.x) | ((u32)f2bf(v1.y) << 16);
    o.w = (u32)f2bf(v1.z) | ((u32)f2bf(v1.w) << 16);
    *reinterpret_cast<uint4*>(dst + g * 8) = o;
  }
}

// ---------------------------- router (idx packed t*2+rank) ------------------
__global__ __launch_bounds__(256) void moe_router(
    const float* __restrict__ x, const float* __restrict__ gate_w,
    unsigned short* __restrict__ xb, int* __restrict__ counts,
    int* __restrict__ list_idx, float* __restrict__ list_w)
{
  const int lane = threadIdx.x & 63;
  const int wave = threadIdx.x >> 6;
  const int t = blockIdx.x * 4 + wave;

  float acc[kExperts];
#pragma unroll
  for (int e = 0; e < kExperts; ++e) acc[e] = 0.f;

  const float4* xrow = reinterpret_cast<const float4*>(x + (size_t)t * kHidden);
#pragma unroll
  for (int j = 0; j < 8; ++j) {
    float4 xv = xrow[j * 64 + lane];
    uint2 pk;
    pk.x = (u32)f2bf(xv.x) | ((u32)f2bf(xv.y) << 16);
    pk.y = (u32)f2bf(xv.z) | ((u32)f2bf(xv.w) << 16);
    *reinterpret_cast<uint2*>(xb + (size_t)t * kHidden + j * 256 + lane * 4) = pk;
#pragma unroll
    for (int e = 0; e < kExperts; ++e) {
      float4 gv = reinterpret_cast<const float4*>(gate_w + (size_t)e * kHidden)[j * 64 + lane];
      acc[e] += xv.x * gv.x + xv.y * gv.y + xv.z * gv.z + xv.w * gv.w;
    }
  }
#pragma unroll
  for (int e = 0; e < kExperts; ++e) {
#pragma unroll
    for (int m = 32; m >= 1; m >>= 1) acc[e] += __shfl_xor(acc[e], m);
  }
  if (lane == 0) {
    float mx = acc[0];
#pragma unroll
    for (int e = 1; e < kExperts; ++e) mx = fmaxf(mx, acc[e]);
    float p[kExperts]; float s = 0.f;
#pragma unroll
    for (int e = 0; e < kExperts; ++e) { p[e] = __expf(acc[e] - mx); s += p[e]; }
    float inv = 1.f / s;
    int i1 = 0; float v1 = p[0];
#pragma unroll
    for (int e = 1; e < kExperts; ++e) if (p[e] > v1) { v1 = p[e]; i1 = e; }
    int i2 = (i1 == 0) ? 1 : 0; float v2 = p[i2];
#pragma unroll
    for (int e = 0; e < kExperts; ++e) {
      if (e == i1 || e == i2) continue;
      if (p[e] > v2) { v2 = p[e]; i2 = e; }
    }
    int s1 = atomicAdd(&counts[i1], 1);
    list_idx[i1 * kTokens + s1] = t * 2 + 0;
    list_w [i1 * kTokens + s1] = v1 * inv;
    int s2 = atomicAdd(&counts[i2], 1);
    list_idx[i2 * kTokens + s2] = t * 2 + 1;
    list_w [i2 * kTokens + s2] = v2 * inv;
  }
}

// ------------------- tile mapping helper -------------------
__device__ __forceinline__ bool map_tile(const int* __restrict__ counts, int mt,
                                         int& e, int& lm, int& sb, int& ne)
{
  int tb = 0; sb = 0;
  for (e = 0; e < kExperts; ++e) {
    ne = counts[e];
    int tiles = (ne + BM - 1) / BM;
    if (mt < tb + tiles) { lm = mt - tb; return true; }
    tb += tiles; sb += ne;
  }
  return false;
}

// ---------------------------- GU GEMM (byte-exact r2, 625us) ----------------
__global__ __launch_bounds__(256, 2) void moe_gu(
    const unsigned short* __restrict__ xb,
    const unsigned short* __restrict__ w1b, const unsigned short* __restrict__ w3b,
    const int* __restrict__ counts, const int* __restrict__ list_idx,
    unsigned short* __restrict__ hbuf)
{
  __shared__ unsigned short As [BM * BK];
  __shared__ unsigned short B1s[BN * BK];
  __shared__ unsigned short B3s[BN * BK];
  __shared__ int toks[BM];

  const int tid = threadIdx.x;
  const int nt  = blockIdx.x / MAX_MT;
  const int mt  = blockIdx.x % MAX_MT;

  int e, lm, sb, ne;
  if (!map_tile(counts, mt, e, lm, sb, ne)) return;
  const int row0 = lm * BM;

  if (tid < BM) {
    int lr = row0 + tid;
    toks[tid] = list_idx[e * kTokens + ((lr < ne) ? lr : 0)] >> 1;
  }
  __syncthreads();

  const int lane = tid & 63;
  const int w = tid >> 6;
  const int wr = w >> 1, wc = w & 1;

  const unsigned short* srcA[4];
  const unsigned short* srcB1[4];
  const unsigned short* srcB3[4];
  const size_t bbase = ((size_t)(e * (kInter / BN) + nt) * (kHidden / BK)) * 1024;
#pragma unroll
  for (int i = 0; i < 4; ++i) {
    int l = (w * 4 + i) * 64 + lane;
    int r = l >> 3, cs = l & 7, c = cs ^ (r & 7);
    srcA[i]  = xb  + (size_t)toks[r] * kHidden + c * 8;
    srcB1[i] = w1b + (bbase + l) * 8;
    srcB3[i] = w3b + (bbase + l) * 8;
  }

  f32x4 accG[4][4], accU[4][4];
  const f32x4 zero = {0.f, 0.f, 0.f, 0.f};
#pragma unroll
  for (int m = 0; m < 4; ++m)
#pragma unroll
    for (int n = 0; n < 4; ++n) { accG[m][n] = zero; accU[m][n] = zero; }

  for (int ks = 0; ks < kHidden / BK; ++ks) {
#pragma unroll
    for (int i = 0; i < 4; ++i) {
      gload16(srcA[i]  + ks * BK,            &As [(w * 4 + i) * 512]);
      gload16(srcB1[i] + (size_t)ks * 8192,  &B1s[(w * 4 + i) * 512]);
      gload16(srcB3[i] + (size_t)ks * 8192,  &B3s[(w * 4 + i) * 512]);
    }
    __syncthreads();
#pragma unroll
    for (int kk = 0; kk < 2; ++kk) {
      const int cq = kk * 4 + (lane >> 4);
      bf16x8 a[4], b1v[4], b3v[4];
#pragma unroll
      for (int m = 0; m < 4; ++m) {
        int row = wr * 64 + m * 16 + (lane & 15);
        a[m] = *reinterpret_cast<const bf16x8*>(&As[row * 64 + ((cq ^ (row & 7)) << 3)]);
      }
#pragma unroll
      for (int n = 0; n < 4; ++n) {
        int row = wc * 64 + n * 16 + (lane & 15);
        b1v[n] = *reinterpret_cast<const bf16x8*>(&B1s[row * 64 + ((cq ^ (row & 7)) << 3)]);
        b3v[n] = *reinterpret_cast<const bf16x8*>(&B3s[row * 64 + ((cq ^ (row & 7)) << 3)]);
      }
#pragma unroll
      for (int m = 0; m < 4; ++m)
#pragma unroll
        for (int n = 0; n < 4; ++n) {
          accG[m][n] = __builtin_amdgcn_mfma_f32_16x16x32_bf16(a[m], b1v[n], accG[m][n], 0, 0, 0);
          accU[m][n] = __builtin_amdgcn_mfma_f32_16x16x32_bf16(a[m], b3v[n], accU[m][n], 0, 0, 0);
        }
    }
    __syncthreads();
  }

#pragma unroll
  for (int m = 0; m < 4; ++m) {
#pragma unroll
    for (int r = 0; r < 4; ++r) {
      int rloc = wr * 64 + m * 16 + ((lane >> 4) * 4) + r;
      int lrow = row0 + rloc;
      if (lrow < ne) {
        size_t base = (size_t)(sb + lrow) * kInter + (size_t)nt * BN + wc * 64 + (lane & 15);
#pragma unroll
        for (int n = 0; n < 4; ++n) {
          float g = accG[m][n][r];
          float u = accU[m][n][r];
          float hv = (g / (1.f + __expf(-g))) * u;
          hbuf[base + n * 16] = f2bf(hv);
        }
      }
    }
  }
}

// ------------- Y GEMM: 128x256 panels, plain stores to ybuf[rank] -----------
// 8 waves: wr=w>>2 row-half (64), wc=w&3 col-quarter (64 of 256). LDS:
// A[128][64]@0, B0[128][64]@16K, B1[128][64]@32K (bytes). 2-barrier r2 loop.
__global__ __launch_bounds__(512, 4) void moe_y5(
    const unsigned short* __restrict__ hbuf,
    const unsigned short* __restrict__ w2b,
    const int* __restrict__ counts, const int* __restrict__ list_idx,
    const float* __restrict__ list_w,
    float* __restrict__ ybuf)
{
  __shared__ unsigned short As[8192];
  __shared__ unsigned short Bs[2][8192];
  __shared__ int   toks[BM];
  __shared__ float cofs[BM];
  __shared__ int   rnks[BM];

  const int tid = threadIdx.x;
  const int nt  = blockIdx.x / MAX_MT;   // nt-major: share w2 panel in L2
  const int mt  = blockIdx.x % MAX_MT;

  int e, lm, sb, ne;
  if (!map_tile(counts, mt, e, lm, sb, ne)) return;
  const int row0 = lm * BM;

  if (tid < BM) {
    int lr = row0 + tid;
    bool v = lr < ne;
    int pk = v ? list_idx[e * kTokens + lr] : 0;
    toks[tid] = pk >> 1;
    rnks[tid] = pk & 1;
    cofs[tid] = v ? list_w[e * kTokens + lr] : 0.f;
  }
  __syncthreads();

  const int lane = tid & 63;
  const int w    = tid >> 6;
  const int wr   = w >> 2;   // 0..1
  const int wc   = w & 3;    // 0..3

  const unsigned short* srcA[2];
  int cOff[2];
#pragma unroll
  for (int j = 0; j < 2; ++j) {
    int l = (w * 2 + j) * 64 + lane;
    int r = l >> 3, c = (l & 7) ^ (r & 7);
    int rg = sb + row0 + r;
    if (rg > kSlotCap - 1) rg = kSlotCap - 1;
    srcA[j] = hbuf + (size_t)rg * kInter + c * 8;
    cOff[j] = l * 8;
  }
  // B halves = 128-row convert panels 2*nt, 2*nt+1 (lp=4, lq=6 layout)
  const unsigned short* pB[2];
#pragma unroll
  for (int h = 0; h < 2; ++h)
    pB[h] = w2b + (size_t)(e * 16 + nt * 2 + h) * NTY * 8192;

  f32x4 acc[4][4];
  const f32x4 zero = {0.f, 0.f, 0.f, 0.f};
#pragma unroll
  for (int m = 0; m < 4; ++m)
#pragma unroll
    for (int n = 0; n < 4; ++n) acc[m][n] = zero;

  for (int ks = 0; ks < NTY; ++ks) {
#pragma unroll
    for (int j = 0; j < 2; ++j) {
      gload16(srcA[j] + ks * BK, &As[(w * 2 + j) * 512]);
      gload16(pB[0] + (size_t)ks * 8192 + cOff[j], &Bs[0][(w * 2 + j) * 512]);
      gload16(pB[1] + (size_t)ks * 8192 + cOff[j], &Bs[1][(w * 2 + j) * 512]);
    }
    __syncthreads();
#pragma unroll
    for (int kk = 0; kk < 2; ++kk) {
      const int cq = kk * 4 + (lane >> 4);
      bf16x8 a[4], b[4];
#pragma unroll
      for (int m = 0; m < 4; ++m) {
        int row = wr * 64 + m * 16 + (lane & 15);
        a[m] = *reinterpret_cast<const bf16x8*>(&As[row * 64 + ((cq ^ (row & 7)) << 3)]);
      }
#pragma unroll
      for (int n = 0; n < 4; ++n) {
        int rr = wc * 64 + n * 16 + (lane & 15);
        int h = rr >> 7, rl = rr & 127;
        b[n] = *reinterpret_cast<const bf16x8*>(&Bs[h][rl * 64 + ((cq ^ (rl & 7)) << 3)]);
      }
#pragma unroll
      for (int m = 0; m < 4; ++m)
#pragma unroll
        for (int n = 0; n < 4; ++n)
          acc[m][n] = __builtin_amdgcn_mfma_f32_16x16x32_bf16(a[m], b[n], acc[m][n], 0, 0, 0);
    }
    __syncthreads();
  }

  // epilogue: plain stores, each (rank,token,col) written exactly once
#pragma unroll
  for (int m = 0; m < 4; ++m) {
#pragma unroll
    for (int r = 0; r < 4; ++r) {
      int rloc = wr * 64 + m * 16 + ((lane >> 4) * 4) + r;
      if (row0 + rloc < ne) {
        float cf = cofs[rloc];
        size_t obase = ((size_t)rnks[rloc] * kTokens + toks[rloc]) * kHidden
                     + (size_t)nt * 256 + wc * 64 + (lane & 15);
#pragma unroll
        for (int n = 0; n < 4; ++n)
          ybuf[obase + n * 16] = cf * acc[m][n][r];
      }
    }
  }
}

// ---------------------------- merge: out = y0 + y1 ----------------------------
__global__ __launch_bounds__(256) void moe_merge(
    const float4* __restrict__ y0, const float4* __restrict__ y1,
    float4* __restrict__ out, int n4)
{
  int stride = gridDim.x * blockDim.x;
  for (int i = blockIdx.x * blockDim.x + threadIdx.x; i < n4; i += stride) {
    float4 a = y0[i], b = y1[i];
    float4 o; o.x = a.x + b.x; o.y = a.y + b.y; o.z = a.z + b.z; o.w = a.w + b.w;
    out[i] = o;
  }
}

// ===================== fallback (fp32 on-the-fly, atomics) ==================
__global__ __launch_bounds__(256, 2) void moe_gu_f32(
    const unsigned short* __restrict__ xb,
    const float* __restrict__ w1, const float* __restrict__ w3,
    const int* __restrict__ counts, const int* __restrict__ list_idx,
    unsigned short* __restrict__ hbuf)
{
  __shared__ unsigned short As [BM * BK];
  __shared__ unsigned short B1s[BN * BK];
  __shared__ unsigned short B3s[BN * BK];
  __shared__ int toks[BM];

  const int tid = threadIdx.x;
  const int nt  = blockIdx.x / MAX_MT;
  const int mt  = blockIdx.x % MAX_MT;

  int e, lm, sb, ne;
  if (!map_tile(counts, mt, e, lm, sb, ne)) return;
  const int row0 = lm * BM;

  if (tid < BM) {
    int lr = row0 + tid;
    toks[tid] = list_idx[e * kTokens + ((lr < ne) ? lr : 0)] >> 1;
  }
  __syncthreads();

  const unsigned short* aptr[4];
#pragma unroll
  for (int i = 0; i < 4; ++i) {
    int chunk = i * 256 + tid;
    int r = chunk >> 3, c8 = chunk & 7;
    aptr[i] = xb + (size_t)toks[r] * kHidden + c8 * 8;
  }
  const float* w1e = w1 + (size_t)e * kInter * kHidden;
  const float* w3e = w3 + (size_t)e * kInter * kHidden;

  f32x4 accG[4][4], accU[4][4];
  const f32x4 zero = {0.f, 0.f, 0.f, 0.f};
#pragma unroll
  for (int m = 0; m < 4; ++m)
#pragma unroll
    for (int n = 0; n < 4; ++n) { accG[m][n] = zero; accU[m][n] = zero; }

  const int lane = tid & 63;
  const int wr = (tid >> 6) >> 1;
  const int wc = (tid >> 6) & 1;

  for (int k0 = 0; k0 < kHidden; k0 += BK) {
#pragma unroll
    for (int i = 0; i < 4; ++i) {
      int chunk = i * 256 + tid;
      uint4 v = *reinterpret_cast<const uint4*>(aptr[i] + k0);
      *reinterpret_cast<uint4*>(&As[chunk * 8]) = v;
    }
#pragma unroll
    for (int i = 0; i < 8; ++i) {
      int c = i * 256 + tid;
      int rowB = c >> 4, c16 = c & 15;
      size_t off = ((size_t)(nt * BN + rowB)) * kHidden + k0 + c16 * 4;
      float4 v1 = *reinterpret_cast<const float4*>(w1e + off);
      float4 v3 = *reinterpret_cast<const float4*>(w3e + off);
      uint2 p1, p3;
      p1.x = (u32)f2bf(v1.x) | ((u32)f2bf(v1.y) << 16);
      p1.y = (u32)f2bf(v1.z) | ((u32)f2bf(v1.w) << 16);
      p3.x = (u32)f2bf(v3.x) | ((u32)f2bf(v3.y) << 16);
      p3.y = (u32)f2bf(v3.z) | ((u32)f2bf(v3.w) << 16);
      *reinterpret_cast<uint2*>(&B1s[rowB * BK + c16 * 4]) = p1;
      *reinterpret_cast<uint2*>(&B3s[rowB * BK + c16 * 4]) = p3;
    }
    __syncthreads();
#pragma unroll
    for (int kk = 0; kk < 2; ++kk) {
      const int klo = kk * 32 + (lane >> 4) * 8;
      bf16x8 a[4], b1v[4], b3v[4];
#pragma unroll
      for (int m = 0; m < 4; ++m)
        a[m] = *reinterpret_cast<const bf16x8*>(&As[(wr * 64 + m * 16 + (lane & 15)) * BK + klo]);
#pragma unroll
      for (int n = 0; n < 4; ++n) {
        b1v[n] = *reinterpret_cast<const bf16x8*>(&B1s[(wc * 64 + n * 16 + (lane & 15)) * BK + klo]);
        b3v[n] = *reinterpret_cast<const bf16x8*>(&B3s[(wc * 64 + n * 16 + (lane & 15)) * BK + klo]);
      }
#pragma unroll
      for (int m = 0; m < 4; ++m)
#pragma unroll
        for (int n = 0; n < 4; ++n) {
          accG[m][n] = __builtin_amdgcn_mfma_f32_16x16x32_bf16(a[m], b1v[n], accG[m][n], 0, 0, 0);
          accU[m][n] = __builtin_amdgcn_mfma_f32_16x16x32_bf16(a[m], b3v[n], accU[m][n], 0, 0, 0);
        }
    }
    __syncthreads();
  }
#pragma unroll
  for (int m = 0; m < 4; ++m) {
#pragma unroll
    for (int r = 0; r < 4; ++r) {
      int rloc = wr * 64 + m * 16 + ((lane >> 4) * 4) + r;
      int lrow = row0 + rloc;
      if (lrow < ne) {
        size_t base = (size_t)(sb + lrow) * kInter + (size_t)nt * BN + wc * 64 + (lane & 15);
#pragma unroll
        for (int n = 0; n < 4; ++n) {
          float g = accG[m][n][r];
          float u = accU[m][n][r];
          hbuf[base + n * 16] = f2bf((g / (1.f + __expf(-g))) * u);
        }
      }
    }
  }
}

__global__ __launch_bounds__(256, 2) void moe_y_f32(
    const unsigned short* __restrict__ hbuf,
    const float* __restrict__ w2,
    const int* __restrict__ counts, const int* __restrict__ list_idx,
    const float* __restrict__ list_w,
    float* __restrict__ out)
{
  __shared__ unsigned short As[BM * BK];
  __shared__ unsigned short Bs[BN * BK];
  __shared__ int   toks[BM];
  __shared__ float cofs[BM];

  const int tid = threadIdx.x;
  const int nt  = blockIdx.x / MAX_MT;
  const int mt  = blockIdx.x % MAX_MT;

  int e, lm, sb, ne;
  if (!map_tile(counts, mt, e, lm, sb, ne)) return;
  const int row0 = lm * BM;

  if (tid < BM) {
    int lr = row0 + tid;
    bool v = lr < ne;
    toks[tid] = v ? (list_idx[e * kTokens + lr] >> 1) : 0;
    cofs[tid] = v ? list_w [e * kTokens + lr] : 0.f;
  }
  __syncthreads();

  const float* w2e = w2 + (size_t)e * kHidden * kInter;
  const unsigned short* arow = hbuf + (size_t)(sb + row0) * kInter;

  f32x4 acc[4][4];
  const f32x4 zero = {0.f, 0.f, 0.f, 0.f};
#pragma unroll
  for (int m = 0; m < 4; ++m)
#pragma unroll
    for (int n = 0; n < 4; ++n) acc[m][n] = zero;

  const int lane = tid & 63;
  const int wr = (tid >> 6) >> 1;
  const int wc = (tid >> 6) & 1;

  for (int k0 = 0; k0 < kInter; k0 += BK) {
#pragma unroll
    for (int i = 0; i < 4; ++i) {
      int chunk = i * 256 + tid;
      int r = chunk >> 3, c8 = chunk & 7;
      uint4 v = *reinterpret_cast<const uint4*>(arow + (size_t)r * kInter + k0 + c8 * 8);
      *reinterpret_cast<uint4*>(&As[chunk * 8]) = v;
    }
#pragma unroll
    for (int i = 0; i < 8; ++i) {
      int c = i * 256 + tid;
      int rowB = c >> 4, c16 = c & 15;
      size_t off = ((size_t)(nt * BN + rowB)) * kInter + k0 + c16 * 4;
      float4 v2 = *reinterpret_cast<const float4*>(w2e + off);
      uint2 p2;
      p2.x = (u32)f2bf(v2.x) | ((u32)f2bf(v2.y) << 16);
      p2.y = (u32)f2bf(v2.z) | ((u32)f2bf(v2.w) << 16);
      *reinterpret_cast<uint2*>(&Bs[rowB * BK + c16 * 4]) = p2;
    }
    __syncthreads();
#pragma unroll
    for (int kk = 0; kk < 2; ++kk) {
      const int klo = kk * 32 + (lane >> 4) * 8;
      bf16x8 a[4], b[4];
#pragma unroll
      for (int m = 0; m < 4; ++m)
        a[m] = *reinterpret_cast<const bf16x8*>(&As[(wr * 64 + m * 16 + (lane & 15)) * BK + klo]);
#pragma unroll
      for (int n = 0; n < 4; ++n)
        b[n] = *reinterpret_cast<const bf16x8*>(&Bs[(wc * 64 + n * 16 + (lane & 15)) * BK + klo]);
#pragma unroll
      for (int m = 0; m < 4; ++m)
#pragma unroll
        for (int n = 0; n < 4; ++n)
          acc[m][n] = __builtin_amdgcn_mfma_f32_16x16x32_bf16(a[m], b[n], acc[m][n], 0, 0, 0);
    }
    __syncthreads();
  }
#pragma unroll
  for (int m = 0; m < 4; ++m) {
#pragma unroll
    for (int r = 0; r < 4; ++r) {
      int rloc = wr * 64 + m * 16 + ((lane >> 4) * 4) + r;
      if (row0 + rloc < ne) {
        float cf = cofs[rloc];
        size_t obase = (size_t)toks[rloc] * kHidden + (size_t)nt * BN + wc * 64 + (lane & 15);
#pragma unroll
        for (int n = 0; n < 4; ++n)
          atomicAdd(&out[obase + n * 16], cf * acc[m][n][r]);
      }
    }
  }
}

// ---------------------------- host ----------------------------
extern "C" void kernel_launch(void* const* d_in, const int* in_sizes, int n_in,
                              void* d_out, int out_size, void* d_ws, size_t ws_size,
                              hipStream_t stream)
{
  const float* x      = (const float*)d_in[0];
  const float* gate_w = (const float*)d_in[1];
  const float* w1     = (const float*)d_in[2];
  const float* w2     = (const float*)d_in[3];
  const float* w3     = (const float*)d_in[4];
  float* out = (float*)d_out;

  char* ws = (char*)d_ws;
  const size_t MiB = 1ull << 20;
  int*   counts   = (int*)(ws);
  int*   list_idx = (int*)(ws + 1024);
  float* list_w   = (float*)(ws + 1024 + kExperts * kTokens * 4);

  hipMemsetAsync(counts, 0, 1024, stream);

  if (ws_size >= 418 * MiB) {
    unsigned short* xb   = (unsigned short*)(ws + 1 * MiB);
    unsigned short* w1b  = (unsigned short*)(ws + 33 * MiB);
    unsigned short* w3b  = (unsigned short*)(ws + 161 * MiB);
    unsigned short* hbuf = (unsigned short*)(ws + 289 * MiB);
    unsigned short* w2b  = w1b;                 // reuse after GU
    float*          ybuf = (float*)(ws + 161 * MiB);  // reuse w3b after GU

    const long nch = (long)kExperts * 32 * 32 * 1024;  // same for all 3 weights
    convert_w<<<4096, 256, 0, stream>>>(w1, w1b, 5, 5, kHidden, nch);
    convert_w<<<4096, 256, 0, stream>>>(w3, w3b, 5, 5, kHidden, nch);
    moe_router<<<kTokens / 4, 256, 0, stream>>>(x, gate_w, xb, counts, list_idx, list_w);
    moe_gu<<<(kInter / BN) * MAX_MT, 256, 0, stream>>>(xb, w1b, w3b, counts, list_idx, hbuf);
    convert_w<<<4096, 256, 0, stream>>>(w2, w2b, 4, 6, kInter, nch);
    moe_y5<<<NPAN_Y5 * MAX_MT, 512, 0, stream>>>(hbuf, w2b, counts, list_idx, list_w, ybuf);
    moe_merge<<<2048, 256, 0, stream>>>(
        (const float4*)ybuf, (const float4*)(ybuf + (size_t)kTokens * kHidden),
        (float4*)out, kTokens * kHidden / 4);
  } else {
    unsigned short* xb   = (unsigned short*)(ws + 1 * MiB);
    unsigned short* hbuf = (unsigned short*)(ws + 36 * MiB);
    hipMemsetAsync(out, 0, (size_t)kTokens * kHidden * sizeof(float), stream);
    moe_router<<<kTokens / 4, 256, 0, stream>>>(x, gate_w, xb, counts, list_idx, list_w);
    moe_gu_f32<<<(kInter / BN) * MAX_MT, 256, 0, stream>>>(xb, w1, w3, counts, list_idx, hbuf);
    moe_y_f32 <<<(kHidden / BN) * MAX_MT, 256, 0, stream>>>(hbuf, w2, counts, list_idx, list_w, out);
  }
}